// Round 3
// baseline (713.837 us; speedup 1.0000x reference)
//
#include <hip/hip_runtime.h>
#include <hip/hip_bf16.h>

#define NN 6144
#define FEATN 128
#define INSM 512
#define HIDN 256
#define DOUT 64

// ---------------------------------------------------------------------------
// Branch MLPs: out = prelu(X@W0+b0, a) @ W1 + b1.   (outputs are FLOAT32)
// blockIdx.y: 0 = local(ori)->out0, 1 = smooth->out1, 2 = hete->emb,u (ws)
// 8 rows per block, 256 threads.
// ---------------------------------------------------------------------------
__global__ __launch_bounds__(256) void mlp_kernel(
    const float* __restrict__ ori, const float* __restrict__ sm,
    const float* __restrict__ W0s, const float* __restrict__ b0s,
    const float* __restrict__ W1s, const float* __restrict__ b1s,
    const float* __restrict__ W0l, const float* __restrict__ b0l,
    const float* __restrict__ W1l, const float* __restrict__ b1l,
    const float* __restrict__ W0h, const float* __restrict__ b0h,
    const float* __restrict__ W1h, const float* __restrict__ b1h,
    const float* __restrict__ am_p, const float* __restrict__ ah_p,
    float* __restrict__ out, float* __restrict__ emb, float* __restrict__ u)
{
    __shared__ float xs[8 * INSM];
    __shared__ float hs[8 * HIDN];
    __shared__ float vals[8 * DOUT];
    const int t = threadIdx.x;
    const int br = blockIdx.y;
    const int r0 = blockIdx.x * 8;

    const float *X, *W0, *b0, *W1, *b1;
    int IN;
    float alpha;
    if (br == 0)      { X = ori; W0 = W0l; b0 = b0l; W1 = W1l; b1 = b1l; IN = FEATN; alpha = am_p[0]; }
    else if (br == 1) { X = sm;  W0 = W0s; b0 = b0s; W1 = W1s; b1 = b1s; IN = INSM;  alpha = am_p[0]; }
    else              { X = sm;  W0 = W0h; b0 = b0h; W1 = W1h; b1 = b1h; IN = INSM;  alpha = ah_p[0]; }

    // rows r0..r0+7 contiguous -> flat float4 copy
    const float* Xb = X + (size_t)r0 * IN;
    const int tot4 = (8 * IN) >> 2;
    for (int i = t; i < tot4; i += 256)
        reinterpret_cast<float4*>(xs)[i] = reinterpret_cast<const float4*>(Xb)[i];
    __syncthreads();

    // layer 1: thread t owns hidden unit t for all 8 rows (k unrolled x4)
    float acc[8];
    #pragma unroll
    for (int r = 0; r < 8; ++r) acc[r] = 0.f;
    for (int k = 0; k < IN; k += 4) {
        const float w0 = W0[(k + 0) * HIDN + t];
        const float w1 = W0[(k + 1) * HIDN + t];
        const float w2 = W0[(k + 2) * HIDN + t];
        const float w3 = W0[(k + 3) * HIDN + t];
        #pragma unroll
        for (int r = 0; r < 8; ++r) {
            float4 x4 = *reinterpret_cast<const float4*>(&xs[r * IN + k]);
            acc[r] = fmaf(x4.x, w0, acc[r]);
            acc[r] = fmaf(x4.y, w1, acc[r]);
            acc[r] = fmaf(x4.z, w2, acc[r]);
            acc[r] = fmaf(x4.w, w3, acc[r]);
        }
    }
    {
        float bb = b0[t];
        #pragma unroll
        for (int r = 0; r < 8; ++r) {
            float h = acc[r] + bb;
            hs[r * HIDN + t] = (h >= 0.f) ? h : alpha * h;   // PReLU
        }
    }
    __syncthreads();

    // layer 2: 512 (row,col) tasks over 256 threads (k unrolled x4)
    for (int task = t; task < 512; task += 256) {
        const int r = task >> 6, c = task & 63;
        float a2 = b1[c];
        for (int k = 0; k < HIDN; k += 4) {
            float4 h4 = *reinterpret_cast<const float4*>(&hs[r * HIDN + k]);
            a2 = fmaf(h4.x, W1[(k + 0) * DOUT + c], a2);
            a2 = fmaf(h4.y, W1[(k + 1) * DOUT + c], a2);
            a2 = fmaf(h4.z, W1[(k + 2) * DOUT + c], a2);
            a2 = fmaf(h4.w, W1[(k + 3) * DOUT + c], a2);
        }
        if (br < 2) {
            float* dst = out + (size_t)br * NN * DOUT;     // FLOAT32 output slots
            dst[(size_t)(r0 + r) * DOUT + c] = a2;
        } else {
            vals[r * DOUT + c] = a2;
        }
    }
    if (br == 2) {
        __syncthreads();
        // softmax each row (64 lanes == 1 wave), then L2-normalize -> u
        const int wv = t >> 6, lane = t & 63;
        #pragma unroll
        for (int rep = 0; rep < 2; ++rep) {
            const int row = wv * 2 + rep;
            float v = vals[row * DOUT + lane];
            float mv = v;
            for (int off = 32; off > 0; off >>= 1) mv = fmaxf(mv, __shfl_xor(mv, off));
            float e = expf(v - mv);
            float ssum = e;
            for (int off = 32; off > 0; off >>= 1) ssum += __shfl_xor(ssum, off);
            float s = e / ssum;
            float n2 = s * s;
            for (int off = 32; off > 0; off >>= 1) n2 += __shfl_xor(n2, off);
            float uu = s * rsqrtf(n2);       // d_i >= 1/64 so max(.,1e-9) never binds
            emb[(size_t)(r0 + row) * DOUT + lane] = v;
            u[(size_t)(r0 + row) * DOUT + lane] = uu;
        }
    }
}

// ---------------------------------------------------------------------------
// Column sums of u in f64 (mean shortcut): mean = (||sum_i u_i||^2 - N) / N^2
// ---------------------------------------------------------------------------
__global__ void colsum_kernel(const float* __restrict__ u, double* __restrict__ colpart)
{
    const int b = blockIdx.x, c = threadIdx.x;
    double a = 0.0;
    for (int i = b; i < NN; i += 64) a += (double)u[(size_t)i * DOUT + c];
    colpart[b * DOUT + c] = a;
}

// ---------------------------------------------------------------------------
// max_{i!=j} u_i . u_j over 64x64 tiles (upper triangle; matrix symmetric).
// ---------------------------------------------------------------------------
__global__ __launch_bounds__(256) void max_kernel(const float* __restrict__ u,
                                                  unsigned int* __restrict__ mx)
{
    const int ti = blockIdx.x, tj = blockIdx.y;
    if (tj < ti) return;
    __shared__ float uit[64 * 64];
    __shared__ float ujt[64 * 64];
    __shared__ float red[4];
    const int t = threadIdx.x;
    const int lrw = t & 15, c4 = t >> 4;
    for (int rr = lrw; rr < 64; rr += 16) {
        float4 va = *reinterpret_cast<const float4*>(&u[((size_t)ti * 64 + rr) * 64 + c4 * 4]);
        uit[(c4 * 4 + 0) * 64 + rr] = va.x;
        uit[(c4 * 4 + 1) * 64 + rr] = va.y;
        uit[(c4 * 4 + 2) * 64 + rr] = va.z;
        uit[(c4 * 4 + 3) * 64 + rr] = va.w;
        float4 vb = *reinterpret_cast<const float4*>(&u[((size_t)tj * 64 + rr) * 64 + c4 * 4]);
        ujt[(c4 * 4 + 0) * 64 + rr] = vb.x;
        ujt[(c4 * 4 + 1) * 64 + rr] = vb.y;
        ujt[(c4 * 4 + 2) * 64 + rr] = vb.z;
        ujt[(c4 * 4 + 3) * 64 + rr] = vb.w;
    }
    __syncthreads();
    const int tx = t & 15, ty = t >> 4;
    float r16[16];
    #pragma unroll
    for (int s = 0; s < 16; ++s) r16[s] = 0.f;
    #pragma unroll 8
    for (int k = 0; k < 64; ++k) {
        float4 a4 = *reinterpret_cast<const float4*>(&uit[k * 64 + ty * 4]);
        float4 b4 = *reinterpret_cast<const float4*>(&ujt[k * 64 + tx * 4]);
        float av[4] = {a4.x, a4.y, a4.z, a4.w};
        float bv[4] = {b4.x, b4.y, b4.z, b4.w};
        #pragma unroll
        for (int aa = 0; aa < 4; ++aa)
            #pragma unroll
            for (int bb = 0; bb < 4; ++bb)
                r16[aa * 4 + bb] = fmaf(av[aa], bv[bb], r16[aa * 4 + bb]);
    }
    float lm = 0.f;
    #pragma unroll
    for (int aa = 0; aa < 4; ++aa)
        #pragma unroll
        for (int bb = 0; bb < 4; ++bb) {
            const int gi = ti * 64 + ty * 4 + aa;
            const int gj = tj * 64 + tx * 4 + bb;
            if (gi != gj) lm = fmaxf(lm, r16[aa * 4 + bb]);
        }
    for (int off = 32; off > 0; off >>= 1) lm = fmaxf(lm, __shfl_xor(lm, off));
    if ((t & 63) == 0) red[t >> 6] = lm;
    __syncthreads();
    if (t == 0) {
        float bm = fmaxf(fmaxf(red[0], red[1]), fmaxf(red[2], red[3]));
        atomicMax(mx, __float_as_uint(bm));   // all candidates > 0
    }
}

__global__ void finalize_kernel(const double* __restrict__ colpart,
                                const unsigned int* __restrict__ mx,
                                float* __restrict__ scal)
{
    const int c = threadIdx.x;   // 64 threads = 1 wave
    double cs = 0.0;
    for (int b = 0; b < 64; ++b) cs += colpart[b * DOUT + c];
    double s2 = cs * cs;
    for (int off = 32; off > 0; off >>= 1) s2 += __shfl_xor(s2, off);
    if (c == 0) {
        double md = (s2 - (double)NN) / ((double)NN * (double)NN);
        float mf = (float)md;
        float mxv = __uint_as_float(mx[0]);
        scal[0] = mf;
        scal[1] = 1.0f / (mxv - mf);
        scal[2] = 1.0f / mf;
    }
}

// ---------------------------------------------------------------------------
// Fused propagation: 384 blocks x 16 output rows; full j-sweep with online
// pos/neg logit accumulation, fused 64-wide softmax, writes out2 (f32).
// ---------------------------------------------------------------------------
__global__ __launch_bounds__(256) void prop_fused_kernel(
    const float* __restrict__ u, const float* __restrict__ emb,
    const float* __restrict__ scal, const float* __restrict__ ah_p,
    float* __restrict__ out3)
{
    __shared__ float ui[16 * 68];     // [i][k]
    __shared__ float ujt[64 * 68];    // [k][j] (transposed)
    __shared__ float embl[64 * 68];   // [j][c]
    __shared__ float vs[16 * 68];     // [i][j] transformed
    __shared__ float red[16 * 64];    // reduction buffer

    const int t = threadIdx.x;
    const int bi = blockIdx.x;
    const float m = scal[0], inv_pd = scal[1], inv_m = scal[2];
    const float alpha = ah_p[0];

    {
        const int i = t >> 4, q = t & 15;
        float4 va = *reinterpret_cast<const float4*>(&u[((size_t)bi * 16 + i) * 64 + q * 4]);
        *reinterpret_cast<float4*>(&ui[i * 68 + q * 4]) = va;
    }

    const int iq  = t >> 6;           // 0..3
    const int jq4 = (t >> 4) & 3;     // 0..3
    const int cq  = t & 15;           // 0..15
    float accp[16], accn[16];
    #pragma unroll
    for (int s = 0; s < 16; ++s) { accp[s] = 0.f; accn[s] = 0.f; }

    const int di = t >> 4;            // dot-phase row 0..15
    const int jq = t & 15;            // dot-phase j-group 0..15

    for (int jt = 0; jt < 96; ++jt) {
        __syncthreads();
        {
            const int q = t & 15;
            #pragma unroll
            for (int it = 0; it < 4; ++it) {
                const int j = (t >> 4) + 16 * it;
                float4 va = *reinterpret_cast<const float4*>(
                    &u[((size_t)jt * 64 + j) * 64 + q * 4]);
                ujt[(q * 4 + 0) * 68 + j] = va.x;
                ujt[(q * 4 + 1) * 68 + j] = va.y;
                ujt[(q * 4 + 2) * 68 + j] = va.z;
                ujt[(q * 4 + 3) * 68 + j] = va.w;
            }
            #pragma unroll
            for (int it = 0; it < 4; ++it) {
                const int qq = t + it * 256;
                const int j = qq >> 4, c4 = qq & 15;
                float4 va = reinterpret_cast<const float4*>(emb + (size_t)jt * 64 * 64)[qq];
                *reinterpret_cast<float4*>(&embl[j * 68 + c4 * 4]) = va;
            }
        }
        __syncthreads();

        {
            float r0 = 0.f, r1 = 0.f, r2 = 0.f, r3 = 0.f;
            #pragma unroll 4
            for (int k = 0; k < 64; ++k) {
                float a = ui[di * 68 + k];
                float4 b = *reinterpret_cast<const float4*>(&ujt[k * 68 + jq * 4]);
                r0 = fmaf(a, b.x, r0);
                r1 = fmaf(a, b.y, r1);
                r2 = fmaf(a, b.z, r2);
                r3 = fmaf(a, b.w, r3);
            }
            const int gi = bi * 16 + di;
            float rr[4] = {r0, r1, r2, r3};
            float4 vv;
            #pragma unroll
            for (int s = 0; s < 4; ++s) {
                const int gj = jt * 64 + jq * 4 + s;
                float lre = (gi == gj) ? 0.f : rr[s];
                float x = lre - m;
                float v = (x > 0.f) ? x * inv_pd : -(lre * inv_m);
                if (gi == gj) v += 1.f;   // add_diag after where
                (&vv.x)[s] = v;
            }
            *reinterpret_cast<float4*>(&vs[di * 68 + jq * 4]) = vv;
        }
        __syncthreads();

        #pragma unroll 4
        for (int n = 0; n < 16; ++n) {
            const int jj = jq4 + n * 4;
            float4 e = *reinterpret_cast<const float4*>(&embl[jj * 68 + cq * 4]);
            float ev[4] = {e.x, e.y, e.z, e.w};
            #pragma unroll
            for (int si = 0; si < 4; ++si) {
                float v = vs[(iq * 4 + si) * 68 + jj];
                float p  = (v >= 0.f) ? v : alpha * v;
                float nv = -v;
                float ng = (nv >= 0.f) ? nv : alpha * nv;
                #pragma unroll
                for (int sc = 0; sc < 4; ++sc) {
                    accp[si * 4 + sc] = fmaf(p,  ev[sc], accp[si * 4 + sc]);
                    accn[si * 4 + sc] = fmaf(ng, ev[sc], accn[si * 4 + sc]);
                }
            }
        }
    }

    const int row = t >> 4, c4 = t & 15;
    float pp[4], pn[4];

    #pragma unroll
    for (int g = 0; g < 4; ++g) {
        __syncthreads();
        if (jq4 == g) {
            #pragma unroll
            for (int si = 0; si < 4; ++si)
                #pragma unroll
                for (int sc = 0; sc < 4; ++sc) {
                    const int idx = (iq * 4 + si) * 64 + cq * 4 + sc;
                    if (g == 0) red[idx] = accp[si * 4 + sc];
                    else        red[idx] += accp[si * 4 + sc];
                }
        }
    }
    __syncthreads();
    {
        float4 lp = *reinterpret_cast<const float4*>(&red[row * 64 + c4 * 4]);
        float mp = fmaxf(fmaxf(lp.x, lp.y), fmaxf(lp.z, lp.w));
        for (int off = 8; off >= 1; off >>= 1) mp = fmaxf(mp, __shfl_xor(mp, off));
        float e0 = __expf(lp.x - mp), e1 = __expf(lp.y - mp),
              e2 = __expf(lp.z - mp), e3 = __expf(lp.w - mp);
        float ssum = e0 + e1 + e2 + e3;
        for (int off = 8; off >= 1; off >>= 1) ssum += __shfl_xor(ssum, off);
        float inv = 1.f / ssum;
        pp[0] = e0 * inv; pp[1] = e1 * inv; pp[2] = e2 * inv; pp[3] = e3 * inv;
    }

    #pragma unroll
    for (int g = 0; g < 4; ++g) {
        __syncthreads();
        if (jq4 == g) {
            #pragma unroll
            for (int si = 0; si < 4; ++si)
                #pragma unroll
                for (int sc = 0; sc < 4; ++sc) {
                    const int idx = (iq * 4 + si) * 64 + cq * 4 + sc;
                    if (g == 0) red[idx] = accn[si * 4 + sc];
                    else        red[idx] += accn[si * 4 + sc];
                }
        }
    }
    __syncthreads();
    {
        float4 ln = *reinterpret_cast<const float4*>(&red[row * 64 + c4 * 4]);
        float mn = fmaxf(fmaxf(ln.x, ln.y), fmaxf(ln.z, ln.w));
        for (int off = 8; off >= 1; off >>= 1) mn = fmaxf(mn, __shfl_xor(mn, off));
        float e0 = __expf(ln.x - mn), e1 = __expf(ln.y - mn),
              e2 = __expf(ln.z - mn), e3 = __expf(ln.w - mn);
        float ssum = e0 + e1 + e2 + e3;
        for (int off = 8; off >= 1; off >>= 1) ssum += __shfl_xor(ssum, off);
        float inv = 1.f / ssum;
        pn[0] = e0 * inv; pn[1] = e1 * inv; pn[2] = e2 * inv; pn[3] = e3 * inv;
    }

    {
        const size_t gi = (size_t)bi * 16 + row;
        float4 eb = *reinterpret_cast<const float4*>(&emb[gi * 64 + c4 * 4]);
        float ev[4] = {eb.x, eb.y, eb.z, eb.w};
        float* dst = out3 + gi * 64 + c4 * 4;
        #pragma unroll
        for (int s = 0; s < 4; ++s)
            dst[s] = 0.5f * (pp[s] - pn[s] + ev[s]);
    }
}

extern "C" void kernel_launch(void* const* d_in, const int* in_sizes, int n_in,
                              void* d_out, int out_size, void* d_ws, size_t ws_size,
                              hipStream_t stream)
{
    (void)in_sizes; (void)n_in; (void)out_size; (void)ws_size;
    const float* ori = (const float*)d_in[0];
    const float* sm  = (const float*)d_in[1];
    // d_in[2] processed_feature: unused; d_in[3] universal_re: unused (BETA=0)
    const float* W0s = (const float*)d_in[4];
    const float* b0s = (const float*)d_in[5];
    const float* W1s = (const float*)d_in[6];
    const float* b1s = (const float*)d_in[7];
    const float* W0l = (const float*)d_in[8];
    const float* b0l = (const float*)d_in[9];
    const float* W1l = (const float*)d_in[10];
    const float* b1l = (const float*)d_in[11];
    const float* W0h = (const float*)d_in[12];
    const float* b0h = (const float*)d_in[13];
    const float* W1h = (const float*)d_in[14];
    const float* b1h = (const float*)d_in[15];
    const float* amp = (const float*)d_in[16];
    const float* ahp = (const float*)d_in[17];

    float* out = (float*)d_out;                    // FLOAT32 output (ref dtype)
    float* ws = (float*)d_ws;
    float* emb = ws;                                        // 393216 f32
    float* u   = ws + (size_t)NN * DOUT;                    // 393216 f32
    double* colpart = (double*)(ws + (size_t)2 * NN * DOUT);        // 4096 f64
    unsigned int* mx = (unsigned int*)(ws + (size_t)2 * NN * DOUT + 8192);
    float* scal = ws + (size_t)2 * NN * DOUT + 8192 + 4;    // 3 f32
    // total ws footprint: ~3.2 MB

    hipMemsetAsync(mx, 0, 4, stream);
    mlp_kernel<<<dim3(NN / 8, 3), 256, 0, stream>>>(
        ori, sm, W0s, b0s, W1s, b1s, W0l, b0l, W1l, b1l,
        W0h, b0h, W1h, b1h, amp, ahp, out, emb, u);
    colsum_kernel<<<64, 64, 0, stream>>>(u, colpart);
    max_kernel<<<dim3(96, 96), 256, 0, stream>>>(u, mx);
    finalize_kernel<<<1, 64, 0, stream>>>(colpart, mx, scal);
    prop_fused_kernel<<<NN / 16, 256, 0, stream>>>(u, emb, scal, ahp,
                                                   out + (size_t)2 * NN * DOUT);
}